// Round 1
// 17018.675 us; speedup vs baseline: 1.1152x; 1.1152x over previous
//
#include <hip/hip_runtime.h>

#define HD 512
#define BB 1024
#define TT 512
#define PP 96
#define DIN 32
#define KC_H 16
#define NBLK 256
#define GRPB 16  // blocks per row-group barrier (all 16 jb of one row group)

typedef unsigned short u16;
typedef __attribute__((ext_vector_type(8))) short bf16x8;
typedef __attribute__((ext_vector_type(4))) float f32x4;
typedef __attribute__((address_space(3))) unsigned int lds_u32;
typedef __attribute__((address_space(3))) u16 lds_u16;
typedef __attribute__((address_space(1))) unsigned int glb_u32;

#define WAIT_VM(N) asm volatile("s_waitcnt vmcnt(" #N ")" ::: "memory")
__device__ __forceinline__ void bar_raw() { asm volatile("s_barrier" ::: "memory"); }

__device__ __forceinline__ float bf2f(u16 s) {
  return __uint_as_float(((unsigned)s) << 16);
}
__device__ __forceinline__ u16 f2bf_rne(float f) {
  unsigned u = __float_as_uint(f);
  u += 0x7FFF + ((u >> 16) & 1);
  return (u16)(u >> 16);
}
__device__ __forceinline__ float sigm(float v) { return 1.f / (1.f + __expf(-v)); }
__device__ __forceinline__ float tanh_(float a) {
  return 1.f - 2.f / (__expf(2.f * a) + 1.f);
}

// ---- coherent (L2-bypass) access helpers: sc0 sc1 ----
__device__ __forceinline__ bf16x8 load_sc16(const u16* p) {
  bf16x8 r;
  asm volatile("global_load_dwordx4 %0, %1, off sc0 sc1" : "=&v"(r) : "v"(p) : "memory");
  return r;
}
__device__ __forceinline__ void store_sc_u16(u16* p, unsigned v) {
  asm volatile("global_store_short %0, %1, off sc0 sc1" :: "v"(p), "v"(v) : "memory");
}
__device__ __forceinline__ void store_sc_f32(float* p, float v) {
  asm volatile("global_store_dword %0, %1, off sc0 sc1" :: "v"(p), "v"(v) : "memory");
}
__device__ __forceinline__ float load_sc_f32w(const float* p) {  // load + full wait
  float v;
  asm volatile("global_load_dword %0, %1, off sc0 sc1\ns_waitcnt vmcnt(0)"
               : "=&v"(v) : "v"(p) : "memory");
  return v;
}
__device__ __forceinline__ unsigned load_sc_u32w(const unsigned* p) {
  unsigned v;
  asm volatile("global_load_dword %0, %1, off sc0 sc1\ns_waitcnt vmcnt(0)"
               : "=&v"(v) : "v"(p) : "memory");
  return v;
}
__device__ __forceinline__ void store_h_sc(u16* H, u16* L, size_t idx, float hv) {
  u16 hi = (u16)(__float_as_uint(hv) >> 16);  // trunc; lo corrects
  u16 lo = f2bf_rne(hv - bf2f(hi));
  store_sc_u16(H + idx, (unsigned)hi);
  store_sc_u16(L + idx, (unsigned)lo);
}

// Pack fp32 weight W[3H x K] into fc-contiguous MFMA B-frag bf16 hi/lo layout:
// group512 = ((jb*KC + kc)*2 + fc)*6 + (g*2 + s);  u16 off = group*512 + lane*8
__global__ void pack_w_kernel(const float* __restrict__ W, int K,
                              u16* __restrict__ out) {
  int tid = blockIdx.x * 256 + threadIdx.x;
  int KC = K >> 5;
  int total = 16 * KC * 2 * 6 * 64;
  if (tid >= total) return;
  int lane = tid & 63;
  int rest = tid >> 6;
  int gs = rest % 6; rest /= 6;
  int fc = rest & 1; rest >>= 1;
  int kc = rest % KC;
  int jb = rest / KC;
  int g = gs >> 1, s = gs & 1;
  int j = jb * 32 + fc * 16 + (lane & 15);
  int k = kc * 32 + (lane >> 4) * 8;
  const float* src = W + (size_t)(g * HD + j) * K + k;
  bf16x8 v;
#pragma unroll
  for (int i = 0; i < 8; ++i) {
    float f = src[i];
    u16 hi = f2bf_rne(f);
    v[i] = (short)((s == 0) ? hi : f2bf_rne(f - bf2f(hi)));
  }
  *(bf16x8*)(out + (size_t)tid * 8) = v;
}

struct AF { bf16x8 h[2]; bf16x8 l[2]; };

__device__ __forceinline__ void fence_af(AF& a) {
  asm volatile("" : "+v"(a.h[0]), "+v"(a.h[1]), "+v"(a.l[0]), "+v"(a.l[1]));
}
// 4 sc1 loads, exact issue order (volatile) for vmcnt accounting.
__device__ __forceinline__ void load_af_sc(AF& a, const u16* aH0, const u16* aL0, int kc) {
  const u16* p = aH0 + kc * 32;
  const u16* q = aL0 + kc * 32;
  a.h[0] = load_sc16(p);
  a.h[1] = load_sc16(p + 16 * HD);
  a.l[0] = load_sc16(q);
  a.l[1] = load_sc16(q + 16 * HD);
}

// 18 MFMAs for one kc from an LDS slot (3072 u16: (g*2+s)*512 + lane*8).
__device__ __forceinline__ void mfma_kc_l(const lds_u16* base, int lane,
                                          const AF& a, f32x4* aR, f32x4* aZ, f32x4* aN) {
  typedef __attribute__((address_space(3))) const bf16x8 lds_bf16x8;
  const lds_u16* p = base + lane * 8;
#pragma unroll
  for (int g = 0; g < 3; ++g) {
    f32x4* acc = (g == 0) ? aR : (g == 1) ? aZ : aN;
    bf16x8 whi = *(lds_bf16x8*)(p + (g * 2 + 0) * 512);
    bf16x8 wlo = *(lds_bf16x8*)(p + (g * 2 + 1) * 512);
#pragma unroll
    for (int s = 0; s < 2; ++s) {
      acc[s] = __builtin_amdgcn_mfma_f32_16x16x32_bf16(a.h[s], whi, acc[s], 0, 0, 0);
      acc[s] = __builtin_amdgcn_mfma_f32_16x16x32_bf16(a.l[s], whi, acc[s], 0, 0, 0);
      acc[s] = __builtin_amdgcn_mfma_f32_16x16x32_bf16(a.h[s], wlo, acc[s], 0, 0, 0);
    }
  }
}
// Same from global (x-phase weights, L2-hot, compiler-managed waits).
__device__ __forceinline__ void mfma_kc_g(const u16* base, int lane,
                                          const AF& a, f32x4* aR, f32x4* aZ, f32x4* aN) {
  const u16* p = base + lane * 8;
#pragma unroll
  for (int g = 0; g < 3; ++g) {
    f32x4* acc = (g == 0) ? aR : (g == 1) ? aZ : aN;
    bf16x8 whi = *(const bf16x8*)(p + (g * 2 + 0) * 512);
    bf16x8 wlo = *(const bf16x8*)(p + (g * 2 + 1) * 512);
#pragma unroll
    for (int s = 0; s < 2; ++s) {
      acc[s] = __builtin_amdgcn_mfma_f32_16x16x32_bf16(a.h[s], whi, acc[s], 0, 0, 0);
      acc[s] = __builtin_amdgcn_mfma_f32_16x16x32_bf16(a.l[s], whi, acc[s], 0, 0, 0);
      acc[s] = __builtin_amdgcn_mfma_f32_16x16x32_bf16(a.h[s], wlo, acc[s], 0, 0, 0);
    }
  }
}

// 6 x 1KB LDS-DMA of one 6KB weight chunk (normal cached reads -> L2-hot).
__device__ __forceinline__ void stage6(const u16* src, u16* dst, int lane) {
#pragma unroll
  for (int j = 0; j < 6; ++j)
    __builtin_amdgcn_global_load_lds((const glb_u32*)(src + j * 512 + lane * 8),
                                     (lds_u32*)(dst + j * 512), 16, 0, 0);
}

// K=512 GEMM phase. 4-pair LDS ring (pair = 12KB: matA | matB), prologue 3,
// lead 3. Stager bundle = 12(DUAL)/6 W-DMAs + 4 A-loads; consumer = 4 A-loads.
// Raw s_barrier handoff; manual vmcnt; no __syncthreads, no fences.
template <bool DUAL>
__device__ __forceinline__ void pipe_phase(
    u16* ringfc, const u16* Ahi, const u16* Alo,
    const u16* WA, const u16* WB, int row0w, int lane, bool stg,
    f32x4* aR, f32x4* aZ, f32x4* aN,
    f32x4* bR, f32x4* bZ, f32x4* bN) {
  const int quad = lane >> 4, n16 = lane & 15;
  const u16* aH0 = Ahi + (size_t)(row0w + n16) * HD + quad * 8;
  const u16* aL0 = Alo + (size_t)(row0w + n16) * HD + quad * 8;
  u16* pb[4] = {ringfc, ringfc + 6144, ringfc + 2 * 6144, ringfc + 3 * 6144};
  AF a0, a1, a2, a3;

  auto issueB = [&](int ikc, u16* pair, AF& dst) {
    if (stg) {
      stage6(WA + (size_t)ikc * 6144, pair, lane);
      if constexpr (DUAL) stage6(WB + (size_t)ikc * 6144, pair + 3072, lane);
    }
    load_af_sc(dst, aH0, aL0, ikc);
  };
  auto cons = [&](u16* pair, AF& a) {
    fence_af(a);
    mfma_kc_l((const lds_u16*)pair, lane, a, aR, aZ, aN);
    if constexpr (DUAL) mfma_kc_l((const lds_u16*)(pair + 3072), lane, a, bR, bZ, bN);
  };
  auto wsteady = [&]() {  // oldest of 3 bundles done -> 2 bundles outstanding
    if (stg) { if constexpr (DUAL) WAIT_VM(32); else WAIT_VM(20); }
    else WAIT_VM(8);
  };
  auto wtail1 = [&]() {  // 1 bundle outstanding
    if (stg) { if constexpr (DUAL) WAIT_VM(16); else WAIT_VM(10); }
    else WAIT_VM(4);
  };

  WAIT_VM(0);  // drain unrelated vm-ops so bundle counting is exact
  issueB(0, pb[0], a0);
  issueB(1, pb[1], a1);
  issueB(2, pb[2], a2);
#pragma unroll 1
  for (int kc = 0; kc < 12; kc += 4) {
    wsteady(); bar_raw(); issueB(kc + 3, pb[3], a3); cons(pb[0], a0);
    wsteady(); bar_raw(); issueB(kc + 4, pb[0], a0); cons(pb[1], a1);
    wsteady(); bar_raw(); issueB(kc + 5, pb[1], a1); cons(pb[2], a2);
    wsteady(); bar_raw(); issueB(kc + 6, pb[2], a2); cons(pb[3], a3);
  }
  wsteady(); bar_raw(); issueB(15, pb[3], a3); cons(pb[0], a0);  // kc=12
  wsteady(); bar_raw(); cons(pb[1], a1);                         // kc=13
  wtail1();  bar_raw(); cons(pb[2], a2);                         // kc=14
  WAIT_VM(0); bar_raw(); cons(pb[3], a3);                        // kc=15
}

// x-phase for encoder L0: fp32 x[B,T,32], K=32, weights/x normal (L2-hot).
__device__ __forceinline__ void x_phase(const float* x, int t, const u16* Wp,
                                        int jb, int fc, int row0w, int lane,
                                        f32x4* aR, f32x4* aZ, f32x4* aN) {
  const int quad = lane >> 4, n16 = lane & 15;
  AF ax;
#pragma unroll
  for (int s = 0; s < 2; ++s) {
    const float* xp = x + (size_t)(row0w + s * 16 + n16) * (TT * DIN) +
                      (size_t)t * DIN + quad * 8;
    f32x4 v0 = *(const f32x4*)xp;
    f32x4 v1 = *(const f32x4*)(xp + 4);
    bf16x8 hi, lo;
#pragma unroll
    for (int i = 0; i < 8; ++i) {
      float f = (i < 4) ? v0[i] : v1[i - 4];
      u16 h = (u16)(__float_as_uint(f) >> 16);
      hi[i] = (short)h;
      lo[i] = (short)f2bf_rne(f - bf2f(h));
    }
    ax.h[s] = hi;
    ax.l[s] = lo;
  }
  mfma_kc_g(Wp + ((size_t)jb * 2 + fc) * 3072, lane, ax, aR, aZ, aN);
}

// Row-group barrier (16 blocks sharing row0): every cross-block dependency in
// this kernel is row-preserving (h1/h2/yfull reads touch only the block's own
// 64 rows, written by the 16 same-row0 blocks), so a 16-block barrier on a
// private counter line suffices. No cache invalidation: sc1 traffic coherent.
__device__ __forceinline__ void gbar(unsigned* gen, unsigned target) {
  WAIT_VM(0);  // all this wave's sc1 stores / atomics globally visible
  __syncthreads();
  if (threadIdx.x == 0) {
    atomicAdd(gen, 1u);  // device-scope by default
    while (load_sc_u32w(gen) < target) __builtin_amdgcn_s_sleep(2);
  }
  __syncthreads();
}

// GRU epilogue with register-resident own-tile h (ho never re-read from mem).
__device__ __forceinline__ void gru_epi_reg(
    const float* bi, const float* bh, float (*ht)[4],
    u16* hnH, u16* hnL, int col, int row0w, int quad,
    const f32x4* aR, const f32x4* aZ, const f32x4* aNX, const f32x4* aNH) {
  const float bir = bi[col],          bhr = bh[col];
  const float biz = bi[HD + col],     bhz = bh[HD + col];
  const float bin = bi[2 * HD + col], bhn = bh[2 * HD + col];
#pragma unroll
  for (int s = 0; s < 2; ++s)
#pragma unroll
    for (int r = 0; r < 4; ++r) {
      const int row = row0w + s * 16 + quad * 4 + r;
      const size_t idx = (size_t)row * HD + col;
      float rr = sigm(aR[s][r] + bir + bhr);
      float zz = sigm(aZ[s][r] + biz + bhz);
      float nn = tanh_(aNX[s][r] + bin + rr * (aNH[s][r] + bhn));
      float hv = (1.f - zz) * nn + zz * ht[s][r];
      ht[s][r] = hv;
      store_h_sc(hnH, hnL, idx, hv);
    }
}

__global__ __launch_bounds__(256, 1)
void gru_persistent_kernel(
    const float* x,
    const u16* pkX0, const u16* pkH0, const float* bi0, const float* bh0,
    const u16* pkX1, const u16* pkH1, const float* bi1, const float* bh1,
    const u16* pkD0H, const float* dbi0, const float* dbh0, const float* dW0,
    const u16* pkD1I, const u16* pkD1H, const float* dbi1, const float* dbh1,
    const float* outW, const float* outb, const float* dstart,
    u16* h1aH, u16* h1aL, u16* h1bH, u16* h1bL,
    u16* h2aH, u16* h2aL, u16* h2bH, u16* h2bL,
    float* yfull, float* dout, unsigned* gen) {
  __shared__ u16 ring[2][4][6144];  // 96 KB: per-fc 4-pair weight ring
  const int b = blockIdx.x;
  const int jb = (b & 7) * 2 + ((b >> 3) & 1);  // XCD-local jb
  const int row0 = (b >> 4) * 64;
  const int tid = threadIdx.x, wave = tid >> 6, lane = tid & 63;
  const int quad = lane >> 4, n16 = lane & 15;
  const int fc = wave & 1, rowg = wave >> 1;
  const bool stg = (rowg == 0);
  const int row0w = row0 + rowg * 32;
  const int col = jb * 32 + fc * 16 + n16;
  u16* ringfc = &ring[fc][0][0];
  const f32x4 z4 = {0.f, 0.f, 0.f, 0.f};
  const size_t woff = ((size_t)jb * KC_H * 2 + fc) * 3072;  // kc stride 6144
  // Per-row-group barrier counter: one u32 per group, 256-B line separation.
  unsigned* geng = gen + ((b >> 4) << 6);

  u16 *h1cH = h1aH, *h1cL = h1aL, *h1nH = h1bH, *h1nL = h1bL;
  u16 *h2cH = h2aH, *h2cL = h2aL, *h2nH = h2bH, *h2nL = h2bL;
  float ht1[2][4] = {{0, 0, 0, 0}, {0, 0, 0, 0}};  // own h1 tile (regs)
  float ht2[2][4] = {{0, 0, 0, 0}, {0, 0, 0, 0}};  // own h2 tile (regs)
  unsigned it = 0;

  // ---- encoder: 513 skewed phases; fused h1c stream feeds L0-h AND L1-x ----
  for (int k = 0; k <= TT; ++k) {
    f32x4 R0[2] = {z4, z4}, Z0[2] = {z4, z4}, NX0[2] = {z4, z4}, NH0[2] = {z4, z4};
    f32x4 R1[2] = {z4, z4}, Z1[2] = {z4, z4}, NX1[2] = {z4, z4}, NH1[2] = {z4, z4};
    if (k > 0 && k < TT) {
      pipe_phase<true>(ringfc, h1cH, h1cL, pkH0 + woff, pkX1 + woff,
                       row0w, lane, stg, R0, Z0, NH0, R1, Z1, NX1);
    } else if (k == 0) {
      pipe_phase<false>(ringfc, h1cH, h1cL, pkH0 + woff, pkH0 + woff,
                        row0w, lane, stg, R0, Z0, NH0, R1, Z1, NX1);
    } else {  // k == TT
      pipe_phase<false>(ringfc, h1cH, h1cL, pkX1 + woff, pkX1 + woff,
                        row0w, lane, stg, R1, Z1, NX1, R0, Z0, NH0);
    }
    if (k < TT) {
      x_phase(x, k, pkX0, jb, fc, row0w, lane, R0, Z0, NX0);
      gru_epi_reg(bi0, bh0, ht1, h1nH, h1nL, col, row0w, quad, R0, Z0, NX0, NH0);
    }
    if (k > 0) {
      pipe_phase<false>(ringfc, h2cH, h2cL, pkH1 + woff, pkH1 + woff,
                        row0w, lane, stg, R1, Z1, NH1, R0, Z0, NX0);
      gru_epi_reg(bi1, bh1, ht2, h2nH, h2nL, col, row0w, quad, R1, Z1, NX1, NH1);
    }
    gbar(geng, GRPB * (++it));
    if (k < TT) { u16* t0 = h1cH; h1cH = h1nH; h1nH = t0;
                  u16* t1 = h1cL; h1cL = h1nL; h1nL = t1; }
    if (k > 0)  { u16* t0 = h2cH; h2cH = h2nH; h2nH = t0;
                  u16* t1 = h2cL; h2cL = h2nL; h2nL = t1; }
  }

  // ---- decoder: 96 steps x (L0, L1); y via atomics into yfull[2][BB] ----
  for (int t = 0; t < PP; ++t) {
    {  // dec L0
      f32x4 R[2] = {z4, z4}, Z[2] = {z4, z4}, NH[2] = {z4, z4};
      f32x4 D0[2] = {z4, z4}, D1[2] = {z4, z4}, D2[2] = {z4, z4};
      pipe_phase<false>(ringfc, h1cH, h1cL, pkD0H + woff, pkD0H + woff,
                        row0w, lane, stg, R, Z, NH, D0, D1, D2);
      float yl[2][4] = {{0, 0, 0, 0}, {0, 0, 0, 0}};
      if (t > 0) {
        const float* yb = yfull + ((t - 1) & 1) * BB;
#pragma unroll
        for (int s = 0; s < 2; ++s)
#pragma unroll
          for (int r = 0; r < 4; ++r) {
            const float* p = yb + (row0w + s * 16 + quad * 4 + r);
            asm volatile("global_load_dword %0, %1, off sc0 sc1"
                         : "=&v"(yl[s][r]) : "v"(p) : "memory");
          }
        WAIT_VM(0);
#pragma unroll
        for (int s = 0; s < 2; ++s)
#pragma unroll
          for (int r = 0; r < 4; ++r)
            asm volatile("" : "+v"(yl[s][r]));
      }
      const float ds0 = dstart[0], ob0 = outb[0];
      const float bir = dbi0[col],          bhr = dbh0[col];
      const float biz = dbi0[HD + col],     bhz = dbh0[HD + col];
      const float bin = dbi0[2 * HD + col], bhn = dbh0[2 * HD + col];
      const float w0r = dW0[col], w0z = dW0[HD + col], w0n = dW0[2 * HD + col];
#pragma unroll
      for (int s = 0; s < 2; ++s)
#pragma unroll
        for (int r = 0; r < 4; ++r) {
          const int row = row0w + s * 16 + quad * 4 + r;
          const size_t idx = (size_t)row * HD + col;
          float yv = (t == 0) ? ds0 : (ob0 + yl[s][r]);
          if (t > 0 && jb == 0 && fc == 0 && n16 == 0)
            dout[(size_t)row * PP + (t - 1)] = yv;
          float rr = sigm(R[s][r] + bir + bhr + yv * w0r);
          float zz = sigm(Z[s][r] + biz + bhz + yv * w0z);
          float nn = tanh_(bin + yv * w0n + rr * (NH[s][r] + bhn));
          float hv = (1.f - zz) * nn + zz * ht1[s][r];
          ht1[s][r] = hv;
          store_h_sc(h1nH, h1nL, idx, hv);
        }
    }
    gbar(geng, GRPB * (++it));
    {  // dec L1: x-phase (d1 new) + h-phase (d2); y partials via atomicAdd
      f32x4 R[2] = {z4, z4}, Z[2] = {z4, z4}, NX[2] = {z4, z4}, NH[2] = {z4, z4};
      f32x4 D0[2] = {z4, z4}, D1[2] = {z4, z4}, D2[2] = {z4, z4};
      pipe_phase<false>(ringfc, h1nH, h1nL, pkD1I + woff, pkD1I + woff,
                        row0w, lane, stg, R, Z, NX, D0, D1, D2);
      pipe_phase<false>(ringfc, h2cH, h2cL, pkD1H + woff, pkD1H + woff,
                        row0w, lane, stg, R, Z, NH, D0, D1, D2);
      const float bir = dbi1[col],          bhr = dbh1[col];
      const float biz = dbi1[HD + col],     bhz = dbh1[HD + col];
      const float bin = dbi1[2 * HD + col], bhn = dbh1[2 * HD + col];
      const float wo = outW[col];
      float* yw = yfull + (t & 1) * BB;
      float* yz = yfull + ((t - 1) & 1) * BB;
#pragma unroll
      for (int s = 0; s < 2; ++s)
#pragma unroll
        for (int r = 0; r < 4; ++r) {
          const int row = row0w + s * 16 + quad * 4 + r;
          const size_t idx = (size_t)row * HD + col;
          float rr = sigm(R[s][r] + bir + bhr);
          float zz = sigm(Z[s][r] + biz + bhz);
          float nn = tanh_(NX[s][r] + bin + rr * (NH[s][r] + bhn));
          float hv = (1.f - zz) * nn + zz * ht2[s][r];
          ht2[s][r] = hv;
          store_h_sc(h2nH, h2nL, idx, hv);
          float v = hv * wo;
#pragma unroll
          for (int off = 1; off < 16; off <<= 1) v += __shfl_xor(v, off, 16);
          if (n16 == 0) {
            atomicAdd(yw + row, v);
            // zero last parity (read by dec L0 this iter; rewritten at t+1)
            if (t > 0 && jb == 0 && fc == 0) store_sc_f32(yz + row, 0.f);
          }
        }
    }
    gbar(geng, GRPB * (++it));
    { u16* t0 = h1cH; h1cH = h1nH; h1nH = t0;
      u16* t1 = h1cL; h1cL = h1nL; h1nL = t1; }
    { u16* t0 = h2cH; h2cH = h2nH; h2nH = t0;
      u16* t1 = h2cL; h2cL = h2nL; h2nL = t1; }
  }

  // ---- finalize: y(P-1), group-local (each group's jb==0 block owns its
  // 64 rows; last gbar guarantees peer atomicAdds are visible) ----
  if ((b & 15) == 0 && tid < 64) {
    int row = row0 + tid;
    float v = load_sc_f32w(yfull + ((PP - 1) & 1) * BB + row);
    dout[(size_t)row * PP + (PP - 1)] = outb[0] + v;
  }
}

extern "C" void kernel_launch(void* const* d_in, const int* in_sizes, int n_in,
                              void* d_out, int out_size, void* d_ws, size_t ws_size,
                              hipStream_t stream) {
  const float* x      = (const float*)d_in[0];
  const float* eW_ih0 = (const float*)d_in[1];
  const float* eW_hh0 = (const float*)d_in[2];
  const float* eb_ih0 = (const float*)d_in[3];
  const float* eb_hh0 = (const float*)d_in[4];
  const float* eW_ih1 = (const float*)d_in[5];
  const float* eW_hh1 = (const float*)d_in[6];
  const float* eb_ih1 = (const float*)d_in[7];
  const float* eb_hh1 = (const float*)d_in[8];
  const float* dW_ih0 = (const float*)d_in[9];
  const float* dW_hh0 = (const float*)d_in[10];
  const float* db_ih0 = (const float*)d_in[11];
  const float* db_hh0 = (const float*)d_in[12];
  const float* dW_ih1 = (const float*)d_in[13];
  const float* dW_hh1 = (const float*)d_in[14];
  const float* db_ih1 = (const float*)d_in[15];
  const float* db_hh1 = (const float*)d_in[16];
  const float* outW   = (const float*)d_in[17];
  const float* outb   = (const float*)d_in[18];
  const float* dstart = (const float*)d_in[19];
  float* out = (float*)d_out;

  char* w = (char*)d_ws;
  size_t off = 0;
  auto carve = [&](size_t bytes) -> void* {
    void* p = w + off;
    off = (off + bytes + 255) & ~(size_t)255;
    return p;
  };
  u16* h1aH = (u16*)carve((size_t)BB * HD * 2); u16* h1aL = (u16*)carve((size_t)BB * HD * 2);
  u16* h1bH = (u16*)carve((size_t)BB * HD * 2); u16* h1bL = (u16*)carve((size_t)BB * HD * 2);
  u16* h2aH = (u16*)carve((size_t)BB * HD * 2); u16* h2aL = (u16*)carve((size_t)BB * HD * 2);
  u16* h2bH = (u16*)carve((size_t)BB * HD * 2); u16* h2bL = (u16*)carve((size_t)BB * HD * 2);
  float* yfull = (float*)carve((size_t)2 * BB * 4);
  unsigned* gen = (unsigned*)carve(4096);  // 16 group counters, 256-B stride
  auto carve_pack = [&](int K) -> u16* {
    return (u16*)carve((size_t)3 * HD * K * 2 * 2);
  };
  u16* pk_e0ih = carve_pack(DIN);
  u16* pk_e0hh = carve_pack(HD);
  u16* pk_e1ih = carve_pack(HD);
  u16* pk_e1hh = carve_pack(HD);
  u16* pk_d0hh = carve_pack(HD);
  u16* pk_d1ih = carve_pack(HD);
  u16* pk_d1hh = carve_pack(HD);

  hipMemsetAsync(h1aH, 0, (size_t)BB * HD * 2, stream);
  hipMemsetAsync(h1aL, 0, (size_t)BB * HD * 2, stream);
  hipMemsetAsync(h2aH, 0, (size_t)BB * HD * 2, stream);
  hipMemsetAsync(h2aL, 0, (size_t)BB * HD * 2, stream);
  hipMemsetAsync(yfull, 0, (size_t)2 * BB * 4, stream);
  hipMemsetAsync(gen, 0, 4096, stream);

  auto pack = [&](const float* W, int K, u16* dst) {
    int total = 16 * (K >> 5) * 2 * 6 * 64;
    pack_w_kernel<<<(total + 255) / 256, 256, 0, stream>>>(W, K, dst);
  };
  pack(eW_ih0, DIN, pk_e0ih);
  pack(eW_hh0, HD, pk_e0hh);
  pack(eW_ih1, HD, pk_e1ih);
  pack(eW_hh1, HD, pk_e1hh);
  pack(dW_hh0, HD, pk_d0hh);
  pack(dW_ih1, HD, pk_d1ih);
  pack(dW_hh1, HD, pk_d1hh);

  gru_persistent_kernel<<<NBLK, 256, 0, stream>>>(
      x, pk_e0ih, pk_e0hh, eb_ih0, eb_hh0,
      pk_e1ih, pk_e1hh, eb_ih1, eb_hh1,
      pk_d0hh, db_ih0, db_hh0, dW_ih0,
      pk_d1ih, pk_d1hh, db_ih1, db_hh1,
      outW, outb, dstart,
      h1aH, h1aL, h1bH, h1bL, h2aH, h2aL, h2bH, h2bL,
      yfull, out, gen);
}